// Round 3
// baseline (370.223 us; speedup 1.0000x reference)
//
#include <hip/hip_runtime.h>
#include <hip/hip_bf16.h>

// TreeLSTM, fully fused, spill-free budget:
//  - one workgroup per tree (256 trees == 256 CUs), 512 threads (8 waves)
//  - waves column-partitioned: wave w owns output cols 16w..16w+15 everywhere,
//    so cell state c stays in f32 registers (MFMA D-fragment layout) end-to-end
//  - registers: W1/Uf/Uiou per-wave B-frags (16+16+48) + c (<=32) ~= 180 peak
//  - LDS (160 KB exact): Wiou 96K | x/h8 16K | leaf-h 16K | h7 arena 32K
//  - leaf loop fuses levels 9(leaves)+8+7 per 64-leaf chunk; then 7 level_steps

typedef __bf16 bf16x8 __attribute__((ext_vector_type(8)));
typedef float  f32x4  __attribute__((ext_vector_type(4)));

#define MFMA16(a,b,c) __builtin_amdgcn_mfma_f32_16x16x32_bf16((a),(b),(c),0,0,0)

__device__ __forceinline__ float fast_sigmoid(float x){
    return __builtin_amdgcn_rcpf(1.0f + __expf(-x));   // inf-safe
}
__device__ __forceinline__ float fast_tanh(float x){
    float ax = fabsf(x);
    float e  = __expf(-2.0f*ax);                        // (0,1]: no overflow
    float t  = (1.0f - e) * __builtin_amdgcn_rcpf(1.0f + e);
    return x < 0.0f ? -t : t;
}
__device__ __forceinline__ unsigned pack2bf(float a, float b){
    unsigned short ua = __builtin_bit_cast(unsigned short, (__bf16)a);
    unsigned short ub = __builtin_bit_cast(unsigned short, (__bf16)b);
    return (unsigned)ua | ((unsigned)ub << 16);
}
// swizzled byte offset in a [rows][128] bf16 LDS tile (row stride 256B)
__device__ __forceinline__ int swzoff(int row, int kByte){
    return row*256 + (kByte ^ ((row & 7) << 4));
}
// A/B fragment: row = rowBase+(lane&15), elems 32*ks+8*(lane>>4)..+7
__device__ __forceinline__ bf16x8 lds_frag(const char* base, int rowBase, int lane, int ks){
    int row = rowBase + (lane & 15);
    int kB  = ks*64 + ((lane >> 4) << 4);
    return *(const bf16x8*)(base + swzoff(row, kB));
}
// h_cat fragment: rows row0,row0+1 summed (fixed fan-in 2)
__device__ __forceinline__ bf16x8 lds_pair_frag(const char* base, int row0, int q, int ks){
    bf16x8 ha = *(const bf16x8*)(base + swzoff(row0,     ks*64 + q*16));
    bf16x8 hb = *(const bf16x8*)(base + swzoff(row0 + 1, ks*64 + q*16));
    bf16x8 t;
    #pragma unroll
    for (int e=0;e<8;++e) t[e] = (__bf16)((float)ha[e] + (float)hb[e]);
    return t;
}
// weight B-fragment from global f32: row fixed per lane, k = 32ks+8q..+7
__device__ __forceinline__ bf16x8 gfrag(const float* __restrict__ W, int row, int q, int ks){
    const float* p = W + row*128 + ks*32 + q*8;
    f32x4 lo = *(const f32x4*)p;
    f32x4 hi = *(const f32x4*)(p+4);
    bf16x8 t;
    t[0]=(__bf16)lo[0]; t[1]=(__bf16)lo[1]; t[2]=(__bf16)lo[2]; t[3]=(__bf16)lo[3];
    t[4]=(__bf16)hi[0]; t[5]=(__bf16)hi[1]; t[6]=(__bf16)hi[2]; t[7]=(__bf16)hi[3];
    return t;
}
// f32 [rows][128] global -> bf16 swizzled LDS
__device__ __forceinline__ void load_w_lds(char* dst, const float* __restrict__ src,
                                           int rows, int tid){
    int total = rows * 32;
    for (int t = tid; t < total; t += 512){
        int row = t >> 5;
        int kq  = (t & 31) << 2;
        f32x4 v = *(const f32x4*)(src + row*128 + kq);
        unsigned long long val = (unsigned long long)pack2bf(v[0], v[1])
                               | ((unsigned long long)pack2bf(v[2], v[3]) << 32);
        *(unsigned long long*)(dst + swzoff(row, kq*2)) = val;
    }
}

struct UFrags {
    bf16x8 uf[4], ui[4], uo[4], uu[4];
    float bi, bo, bu, bfc;
};

// One tree level with N nodes. Children: 2N rows of h in childR; child c in
// c[] registers, layout L(2N): c[t][m] of lane(q,r) wave w = node 16t+4q+m,
// col 16w+r. Produces L(N) c in-place and writes N rows of h to curR.
template<int N>
__device__ __forceinline__ void level_step(float (&c)[8][4], const char* childR, char* curR,
                                           const UFrags& W, int lane, int colb2){
    const int q = lane >> 4, r = lane & 15;
    constexpr int NCC = (2*N)/16 > 0 ? (2*N)/16 : 1;   // child row chunks
    constexpr int NC  = N/16 > 0 ? N/16 : 1;           // node row chunks
    constexpr int REDN = NCC > 2 ? NCC : 2;
    float red[REDN][2];
    #pragma unroll
    for (int t=NCC;t<REDN;++t){ red[t][0]=0.f; red[t][1]=0.f; }   // tail-safe
    // F: fpre = h_child @ Uf^T; fc = sigmoid(fpre+bf)*c; in-lane pair-sum
    #pragma unroll
    for (int t=0;t<NCC;++t){
        f32x4 acc = {0.f,0.f,0.f,0.f};
        #pragma unroll
        for (int ks=0;ks<4;++ks)
            acc = MFMA16(lds_frag(childR, 16*t, lane, ks), W.uf[ks], acc);
        red[t][0] = fast_sigmoid(acc[0]+W.bfc)*c[t][0] + fast_sigmoid(acc[1]+W.bfc)*c[t][1];
        red[t][1] = fast_sigmoid(acc[2]+W.bfc)*c[t][2] + fast_sigmoid(acc[3]+W.bfc)*c[t][3];
    }
    // fold red (node 8t+2q+j) into L(N) (node 16tau+4q+m')
    #pragma unroll
    for (int tau=0; tau<NC; ++tau){
        #pragma unroll
        for (int mp=0; mp<4; ++mp){
            int s   = 4*q + mp;
            int src = ((s>>1)&3)*16 + r;
            float va = __shfl(red[2*tau  ][mp&1], src, 64);
            float vb = __shfl(red[2*tau+1][mp&1], src, 64);
            c[tau][mp] = (q >= 2) ? vb : va;
        }
    }
    // IOU: iou = (h2j+h2j+1) @ Uiou^T; apply_node with c_red; h -> curR
    #pragma unroll
    for (int tau=0; tau<NC; ++tau){
        f32x4 ai={0.f,0.f,0.f,0.f}, ao=ai, au=ai;
        #pragma unroll
        for (int ks=0;ks<4;++ks){
            bf16x8 a = lds_pair_frag(childR, 32*tau + 2*r, q, ks);
            ai = MFMA16(a, W.ui[ks], ai);
            ao = MFMA16(a, W.uo[ks], ao);
            au = MFMA16(a, W.uu[ks], au);
        }
        #pragma unroll
        for (int m=0;m<4;++m){
            int row = 16*tau + 4*q + m;
            float cv = fast_sigmoid(ai[m]+W.bi)*fast_tanh(au[m]+W.bu) + c[tau][m];
            float hv = fast_sigmoid(ao[m]+W.bo)*fast_tanh(cv);
            c[tau][m] = cv;
            if (N >= 16 || (4*q + m) < N)
                *(__bf16*)(curR + swzoff(row, colb2)) = (__bf16)hv;
        }
    }
    __syncthreads();
}

__global__ __launch_bounds__(512, 2)
void treelstm_fused(const float* __restrict__ feats,
                    const float* __restrict__ W1,   const float* __restrict__ b1,
                    const float* __restrict__ Wiou, const float* __restrict__ Uiou,
                    const float* __restrict__ biou, const float* __restrict__ Uf,
                    const float* __restrict__ bfv,  const float* __restrict__ Wout,
                    const float* __restrict__ bout, float* __restrict__ out)
{
    extern __shared__ char smem[];
    char* wiouL = smem;             // 96K: Wiou bf16 (leaf phase); levels: bufA
    char* stg1  = smem + 98304;     // 16K: x (64 rows); then h8 (32 rows)
    char* stg2  = smem + 114688;    // 16K: leaf h (64 rows); later c_root buf
    char* arena = smem + 131072;    // 32K: h7 (128 rows)

    const int tid  = threadIdx.x;
    const int lane = tid & 63;
    const int wave = tid >> 6;
    const int q    = lane >> 4;
    const int r    = lane & 15;
    const int colw = 16*wave + r;
    const int colb2= 2*colw;
    const int tree = blockIdx.x;

    load_w_lds(wiouL, Wiou, 384, tid);

    UFrags W;
    bf16x8 w1f[4];
    #pragma unroll
    for (int ks=0;ks<4;++ks){
        W.uf[ks] = gfrag(Uf,   colw,     q, ks);
        W.ui[ks] = gfrag(Uiou, colw,     q, ks);
        W.uo[ks] = gfrag(Uiou, 128+colw, q, ks);
        W.uu[ks] = gfrag(Uiou, 256+colw, q, ks);
        w1f[ks]  = gfrag(W1,   colw,     q, ks);
    }
    W.bi = biou[colw]; W.bo = biou[128+colw]; W.bu = biou[256+colw]; W.bfc = bfv[colw];
    const float b1c = b1[colw];

    const float* featsT = feats + ((size_t)tree*1023 + 511)*128;   // leaf rows
    float c[8][4];   // cell state, L(n) layout, f32 end-to-end

    // ---- leaf phase: 8 chunks x 64 leaves, fusing levels 9, 8, 7 ----
    #pragma unroll
    for (int ci=0; ci<8; ++ci){
        // (a) x = relu(feats @ W1^T + b1) -> stg1 (64 rows)
        #pragma unroll
        for (int t=0;t<4;++t){
            f32x4 acc = {0.f,0.f,0.f,0.f};
            #pragma unroll
            for (int ks=0;ks<4;++ks){
                const float* p = featsT + (size_t)(ci*64 + t*16 + r)*128 + ks*32 + q*8;
                f32x4 lo = *(const f32x4*)p;
                f32x4 hi = *(const f32x4*)(p+4);
                bf16x8 a;
                a[0]=(__bf16)lo[0]; a[1]=(__bf16)lo[1]; a[2]=(__bf16)lo[2]; a[3]=(__bf16)lo[3];
                a[4]=(__bf16)hi[0]; a[5]=(__bf16)hi[1]; a[6]=(__bf16)hi[2]; a[7]=(__bf16)hi[3];
                acc = MFMA16(a, w1f[ks], acc);
            }
            #pragma unroll
            for (int m=0;m<4;++m)
                *(__bf16*)(stg1 + swzoff(16*t + 4*q + m, colb2)) = (__bf16)fmaxf(acc[m]+b1c, 0.f);
        }
        __syncthreads();                                    // B1: x ready
        // (b) iou = x @ Wiou^T (Wiou from LDS); apply_node(c_in=0)
        float c0c[4][4];
        #pragma unroll
        for (int t=0;t<4;++t){
            f32x4 ai={0.f,0.f,0.f,0.f}, ao=ai, au=ai;
            #pragma unroll
            for (int ks=0;ks<4;++ks){
                bf16x8 a = lds_frag(stg1, 16*t, lane, ks);
                ai = MFMA16(a, lds_frag(wiouL,       16*wave, lane, ks), ai);
                ao = MFMA16(a, lds_frag(wiouL, 128 + 16*wave, lane, ks), ao);
                au = MFMA16(a, lds_frag(wiouL, 256 + 16*wave, lane, ks), au);
            }
            #pragma unroll
            for (int m=0;m<4;++m){
                float cv = fast_sigmoid(ai[m]+W.bi)*fast_tanh(au[m]+W.bu);
                float hv = fast_sigmoid(ao[m]+W.bo)*fast_tanh(cv);
                c0c[t][m] = cv;
                *(__bf16*)(stg2 + swzoff(16*t + 4*q + m, colb2)) = (__bf16)hv;
            }
        }
        __syncthreads();                                    // B2: leaf h ready
        // (c) leaf F-gates + pair-reduce + fold -> c8loc (32 level-8 nodes)
        float red[4][2];
        #pragma unroll
        for (int t=0;t<4;++t){
            f32x4 acc = {0.f,0.f,0.f,0.f};
            #pragma unroll
            for (int ks=0;ks<4;++ks)
                acc = MFMA16(lds_frag(stg2, 16*t, lane, ks), W.uf[ks], acc);
            red[t][0] = fast_sigmoid(acc[0]+W.bfc)*c0c[t][0] + fast_sigmoid(acc[1]+W.bfc)*c0c[t][1];
            red[t][1] = fast_sigmoid(acc[2]+W.bfc)*c0c[t][2] + fast_sigmoid(acc[3]+W.bfc)*c0c[t][3];
        }
        float c8loc[2][4];
        #pragma unroll
        for (int tau=0;tau<2;++tau){
            #pragma unroll
            for (int mp=0;mp<4;++mp){
                int s   = 4*q + mp;
                int src = ((s>>1)&3)*16 + r;
                float va = __shfl(red[2*tau  ][mp&1], src, 64);
                float vb = __shfl(red[2*tau+1][mp&1], src, 64);
                c8loc[tau][mp] = (q >= 2) ? vb : va;
            }
        }
        // (d) level-8 IOU: h8 (32 rows) -> stg1 (x consumed after B2)
        #pragma unroll
        for (int tau=0;tau<2;++tau){
            f32x4 ai={0.f,0.f,0.f,0.f}, ao=ai, au=ai;
            #pragma unroll
            for (int ks=0;ks<4;++ks){
                bf16x8 a = lds_pair_frag(stg2, 32*tau + 2*r, q, ks);
                ai = MFMA16(a, W.ui[ks], ai);
                ao = MFMA16(a, W.uo[ks], ao);
                au = MFMA16(a, W.uu[ks], au);
            }
            #pragma unroll
            for (int m=0;m<4;++m){
                float cv = fast_sigmoid(ai[m]+W.bi)*fast_tanh(au[m]+W.bu) + c8loc[tau][m];
                float hv = fast_sigmoid(ao[m]+W.bo)*fast_tanh(cv);
                c8loc[tau][m] = cv;
                *(__bf16*)(stg1 + swzoff(16*tau + 4*q + m, colb2)) = (__bf16)hv;
            }
        }
        __syncthreads();                                    // B3: h8 ready
        // (e) level-7 F-gates on h8 + fold -> c7loc (16 level-7 nodes)
        float red7[2][2];
        #pragma unroll
        for (int t=0;t<2;++t){
            f32x4 acc = {0.f,0.f,0.f,0.f};
            #pragma unroll
            for (int ks=0;ks<4;++ks)
                acc = MFMA16(lds_frag(stg1, 16*t, lane, ks), W.uf[ks], acc);
            red7[t][0] = fast_sigmoid(acc[0]+W.bfc)*c8loc[t][0] + fast_sigmoid(acc[1]+W.bfc)*c8loc[t][1];
            red7[t][1] = fast_sigmoid(acc[2]+W.bfc)*c8loc[t][2] + fast_sigmoid(acc[3]+W.bfc)*c8loc[t][3];
        }
        float c7loc[4];
        #pragma unroll
        for (int mp=0;mp<4;++mp){
            int s   = 4*q + mp;
            int src = ((s>>1)&3)*16 + r;
            float va = __shfl(red7[0][mp&1], src, 64);
            float vb = __shfl(red7[1][mp&1], src, 64);
            c7loc[mp] = (q >= 2) ? vb : va;
        }
        // (f) level-7 IOU: h7 (16 rows) -> arena rows 16ci..; c7 -> c[ci]
        {
            f32x4 ai={0.f,0.f,0.f,0.f}, ao=ai, au=ai;
            #pragma unroll
            for (int ks=0;ks<4;++ks){
                bf16x8 a = lds_pair_frag(stg1, 2*r, q, ks);
                ai = MFMA16(a, W.ui[ks], ai);
                ao = MFMA16(a, W.uo[ks], ao);
                au = MFMA16(a, W.uu[ks], au);
            }
            #pragma unroll
            for (int m=0;m<4;++m){
                float cv = fast_sigmoid(ai[m]+W.bi)*fast_tanh(au[m]+W.bu) + c7loc[m];
                float hv = fast_sigmoid(ao[m]+W.bo)*fast_tanh(cv);
                c[ci][m] = cv;
                *(__bf16*)(arena + swzoff(16*ci + 4*q + m, colb2)) = (__bf16)hv;
            }
        }
        __syncthreads();                                    // B4: chunk done
    }

    // ---- levels 6..0: h ping-pongs arena <-> bufA (old Wiou slab) ----
    char* bufA = wiouL;
    level_step<64>(c, arena, bufA,  W, lane, colb2);
    level_step<32>(c, bufA,  arena, W, lane, colb2);
    level_step<16>(c, arena, bufA,  W, lane, colb2);
    level_step< 8>(c, bufA,  arena, W, lane, colb2);
    level_step< 4>(c, arena, bufA,  W, lane, colb2);
    level_step< 2>(c, bufA,  arena, W, lane, colb2);
    level_step< 1>(c, arena, bufA,  W, lane, colb2);

    // ---- out = c_root @ Wout^T + bout ----
    float* cbuf = (float*)stg2;
    if (q == 0) cbuf[colw] = c[0][0];          // root: node 0 lives in q==0,m==0
    __syncthreads();
    if (tid < 32){
        float acc = bout[tid];
        const float* wr = Wout + tid*128;
        #pragma unroll
        for (int k=0;k<128;k+=4){
            f32x4 wv = *(const f32x4*)(wr + k);
            acc += wv[0]*cbuf[k] + wv[1]*cbuf[k+1] + wv[2]*cbuf[k+2] + wv[3]*cbuf[k+3];
        }
        out[tree*32 + tid] = acc;
    }
}

extern "C" void kernel_launch(void* const* d_in, const int* in_sizes, int n_in,
                              void* d_out, int out_size, void* d_ws, size_t ws_size,
                              hipStream_t stream)
{
    (void)in_sizes; (void)n_in; (void)out_size; (void)d_ws; (void)ws_size;
    const float* feats = (const float*)d_in[0];
    const float* W1    = (const float*)d_in[2];
    const float* b1    = (const float*)d_in[3];
    const float* Wiou  = (const float*)d_in[4];
    const float* Uiou  = (const float*)d_in[5];
    const float* biou  = (const float*)d_in[6];
    const float* Uf    = (const float*)d_in[7];
    const float* bf    = (const float*)d_in[8];
    const float* Wout  = (const float*)d_in[9];
    const float* bout  = (const float*)d_in[10];
    float* out = (float*)d_out;

    const int lds = 163840;
    hipFuncSetAttribute((const void*)&treelstm_fused,
                        hipFuncAttributeMaxDynamicSharedMemorySize, lds);
    treelstm_fused<<<dim3(256), dim3(512), lds, stream>>>(
        feats, W1, b1, Wiou, Uiou, biou, Uf, bf, Wout, bout, out);
}

// Round 4
// 337.608 us; speedup vs baseline: 1.0966x; 1.0966x over previous
//
#include <hip/hip_runtime.h>
#include <hip/hip_bf16.h>

// TreeLSTM, fully fused, spill-free budget:
//  - one workgroup per tree (256 trees == 256 CUs), 512 threads (8 waves)
//  - waves column-partitioned: wave w owns output cols 16w..16w+15 everywhere,
//    so cell state c stays in f32 registers (MFMA D-fragment layout) end-to-end
//  - registers: W1/Uf/Uiou per-wave B-frags (16+16+48) + c (<=32) ~= 185 peak
//  - LDS (160 KB exact): Wiou 96K | x/h8 16K | leaf-h 16K | h7 arena 32K
//  - leaf loop fuses levels 9(leaves)+8+7 per 64-leaf chunk (#pragma unroll 1:
//    full unroll caused 29 MB of scratch spills in round 3); then 7 level_steps
//  - swizzle ((row>>1)&7)<<4: pair reads (rows 2r,2r+1) 2-way, frag reads 2-way

typedef __bf16 bf16x8 __attribute__((ext_vector_type(8)));
typedef float  f32x4  __attribute__((ext_vector_type(4)));

#define MFMA16(a,b,c) __builtin_amdgcn_mfma_f32_16x16x32_bf16((a),(b),(c),0,0,0)

__device__ __forceinline__ float fast_sigmoid(float x){
    return __builtin_amdgcn_rcpf(1.0f + __expf(-x));   // inf-safe
}
__device__ __forceinline__ float fast_tanh(float x){
    float ax = fabsf(x);
    float e  = __expf(-2.0f*ax);                        // (0,1]: no overflow
    float t  = (1.0f - e) * __builtin_amdgcn_rcpf(1.0f + e);
    return x < 0.0f ? -t : t;
}
__device__ __forceinline__ unsigned pack2bf(float a, float b){
    unsigned short ua = __builtin_bit_cast(unsigned short, (__bf16)a);
    unsigned short ub = __builtin_bit_cast(unsigned short, (__bf16)b);
    return (unsigned)ua | ((unsigned)ub << 16);
}
// swizzled byte offset in a [rows][128] bf16 LDS tile (row stride 256B).
// (row>>1) variant: pair reads (rows 2r,2r+1) land 2-way, frag reads 2-way.
__device__ __forceinline__ int swzoff(int row, int kByte){
    return row*256 + (kByte ^ (((row >> 1) & 7) << 4));
}
// A/B fragment: row = rowBase+(lane&15), elems 32*ks+8*(lane>>4)..+7
__device__ __forceinline__ bf16x8 lds_frag(const char* base, int rowBase, int lane, int ks){
    int row = rowBase + (lane & 15);
    int kB  = ks*64 + ((lane >> 4) << 4);
    return *(const bf16x8*)(base + swzoff(row, kB));
}
// h_cat fragment: rows row0,row0+1 summed (fixed fan-in 2)
__device__ __forceinline__ bf16x8 lds_pair_frag(const char* base, int row0, int q, int ks){
    bf16x8 ha = *(const bf16x8*)(base + swzoff(row0,     ks*64 + q*16));
    bf16x8 hb = *(const bf16x8*)(base + swzoff(row0 + 1, ks*64 + q*16));
    bf16x8 t;
    #pragma unroll
    for (int e=0;e<8;++e) t[e] = (__bf16)((float)ha[e] + (float)hb[e]);
    return t;
}
// weight B-fragment from global f32: row fixed per lane, k = 32ks+8q..+7
__device__ __forceinline__ bf16x8 gfrag(const float* __restrict__ W, int row, int q, int ks){
    const float* p = W + row*128 + ks*32 + q*8;
    f32x4 lo = *(const f32x4*)p;
    f32x4 hi = *(const f32x4*)(p+4);
    bf16x8 t;
    t[0]=(__bf16)lo[0]; t[1]=(__bf16)lo[1]; t[2]=(__bf16)lo[2]; t[3]=(__bf16)lo[3];
    t[4]=(__bf16)hi[0]; t[5]=(__bf16)hi[1]; t[6]=(__bf16)hi[2]; t[7]=(__bf16)hi[3];
    return t;
}
__device__ __forceinline__ bf16x8 cvt2(f32x4 lo, f32x4 hi){
    bf16x8 t;
    t[0]=(__bf16)lo[0]; t[1]=(__bf16)lo[1]; t[2]=(__bf16)lo[2]; t[3]=(__bf16)lo[3];
    t[4]=(__bf16)hi[0]; t[5]=(__bf16)hi[1]; t[6]=(__bf16)hi[2]; t[7]=(__bf16)hi[3];
    return t;
}
// f32 [rows][128] global -> bf16 swizzled LDS
__device__ __forceinline__ void load_w_lds(char* dst, const float* __restrict__ src,
                                           int rows, int tid){
    int total = rows * 32;
    for (int t = tid; t < total; t += 512){
        int row = t >> 5;
        int kq  = (t & 31) << 2;
        f32x4 v = *(const f32x4*)(src + row*128 + kq);
        unsigned long long val = (unsigned long long)pack2bf(v[0], v[1])
                               | ((unsigned long long)pack2bf(v[2], v[3]) << 32);
        *(unsigned long long*)(dst + swzoff(row, kq*2)) = val;
    }
}

struct UFrags {
    bf16x8 uf[4], ui[4], uo[4], uu[4];
    float bi, bo, bu, bfc;
};

// One tree level with N nodes. Children: 2N rows of h in childR; child c in
// c[] registers, layout L(2N): c[t][m] of lane(q,r) wave w = node 16t+4q+m,
// col 16w+r. Produces L(N) c in-place and writes N rows of h to curR.
template<int N>
__device__ __forceinline__ void level_step(float (&c)[8][4], const char* childR, char* curR,
                                           const UFrags& W, int lane, int colb2){
    const int q = lane >> 4, r = lane & 15;
    constexpr int NCC = (2*N)/16 > 0 ? (2*N)/16 : 1;   // child row chunks
    constexpr int NC  = N/16 > 0 ? N/16 : 1;           // node row chunks
    constexpr int REDN = NCC > 2 ? NCC : 2;
    float red[REDN][2];
    #pragma unroll
    for (int t=NCC;t<REDN;++t){ red[t][0]=0.f; red[t][1]=0.f; }   // tail-safe
    // F: fpre = h_child @ Uf^T; fc = sigmoid(fpre+bf)*c; in-lane pair-sum
    #pragma unroll
    for (int t=0;t<NCC;++t){
        f32x4 acc = {0.f,0.f,0.f,0.f};
        #pragma unroll
        for (int ks=0;ks<4;++ks)
            acc = MFMA16(lds_frag(childR, 16*t, lane, ks), W.uf[ks], acc);
        red[t][0] = fast_sigmoid(acc[0]+W.bfc)*c[t][0] + fast_sigmoid(acc[1]+W.bfc)*c[t][1];
        red[t][1] = fast_sigmoid(acc[2]+W.bfc)*c[t][2] + fast_sigmoid(acc[3]+W.bfc)*c[t][3];
    }
    // fold red (node 8t+2q+j) into L(N) (node 16tau+4q+m')
    #pragma unroll
    for (int tau=0; tau<NC; ++tau){
        #pragma unroll
        for (int mp=0; mp<4; ++mp){
            int s   = 4*q + mp;
            int src = ((s>>1)&3)*16 + r;
            float va = __shfl(red[2*tau  ][mp&1], src, 64);
            float vb = __shfl(red[2*tau+1][mp&1], src, 64);
            c[tau][mp] = (q >= 2) ? vb : va;
        }
    }
    // IOU: iou = (h2j+h2j+1) @ Uiou^T; apply_node with c_red; h -> curR
    #pragma unroll
    for (int tau=0; tau<NC; ++tau){
        f32x4 ai={0.f,0.f,0.f,0.f}, ao=ai, au=ai;
        #pragma unroll
        for (int ks=0;ks<4;++ks){
            bf16x8 a = lds_pair_frag(childR, 32*tau + 2*r, q, ks);
            ai = MFMA16(a, W.ui[ks], ai);
            ao = MFMA16(a, W.uo[ks], ao);
            au = MFMA16(a, W.uu[ks], au);
        }
        #pragma unroll
        for (int m=0;m<4;++m){
            int row = 16*tau + 4*q + m;
            float cv = fast_sigmoid(ai[m]+W.bi)*fast_tanh(au[m]+W.bu) + c[tau][m];
            float hv = fast_sigmoid(ao[m]+W.bo)*fast_tanh(cv);
            c[tau][m] = cv;
            if (N >= 16 || (4*q + m) < N)
                *(__bf16*)(curR + swzoff(row, colb2)) = (__bf16)hv;
        }
    }
    __syncthreads();
}

__global__ __launch_bounds__(512, 2)
void treelstm_fused(const float* __restrict__ feats,
                    const float* __restrict__ W1,   const float* __restrict__ b1,
                    const float* __restrict__ Wiou, const float* __restrict__ Uiou,
                    const float* __restrict__ biou, const float* __restrict__ Uf,
                    const float* __restrict__ bfv,  const float* __restrict__ Wout,
                    const float* __restrict__ bout, float* __restrict__ out)
{
    extern __shared__ char smem[];
    char* wiouL = smem;             // 96K: Wiou bf16 (leaf phase); levels: bufA
    char* stg1  = smem + 98304;     // 16K: x (64 rows); then h8 (32 rows)
    char* stg2  = smem + 114688;    // 16K: leaf h (64 rows); later c_root buf
    char* arena = smem + 131072;    // 32K: h7 (128 rows)

    const int tid  = threadIdx.x;
    const int lane = tid & 63;
    const int wave = tid >> 6;
    const int q    = lane >> 4;
    const int r    = lane & 15;
    const int colw = 16*wave + r;
    const int colb2= 2*colw;
    const int tree = blockIdx.x;

    load_w_lds(wiouL, Wiou, 384, tid);

    UFrags W;
    bf16x8 w1f[4];
    #pragma unroll
    for (int ks=0;ks<4;++ks){
        W.uf[ks] = gfrag(Uf,   colw,     q, ks);
        W.ui[ks] = gfrag(Uiou, colw,     q, ks);
        W.uo[ks] = gfrag(Uiou, 128+colw, q, ks);
        W.uu[ks] = gfrag(Uiou, 256+colw, q, ks);
        w1f[ks]  = gfrag(W1,   colw,     q, ks);
    }
    W.bi = biou[colw]; W.bo = biou[128+colw]; W.bu = biou[256+colw]; W.bfc = bfv[colw];
    const float b1c = b1[colw];

    const float* featsT = feats + ((size_t)tree*1023 + 511)*128;   // leaf rows
    float c[8][4];   // cell state, L(n) layout, f32 end-to-end

    // ---- leaf phase: 8 chunks x 64 leaves, fusing levels 9, 8, 7 ----
    #pragma unroll 1
    for (int ci=0; ci<8; ++ci){
        // (a) x = relu(feats @ W1^T + b1) -> stg1, feats loads pipelined t->t+1
        {
            const float* base = featsT + (size_t)(ci*64 + r)*128 + q*8;
            f32x4 cur[8];
            #pragma unroll
            for (int ks=0;ks<4;++ks){
                cur[2*ks]   = *(const f32x4*)(base + ks*32);
                cur[2*ks+1] = *(const f32x4*)(base + ks*32 + 4);
            }
            #pragma unroll
            for (int t=0;t<4;++t){
                f32x4 nxt[8];
                if (t < 3){
                    const float* bn = base + (size_t)(t+1)*16*128;
                    #pragma unroll
                    for (int ks=0;ks<4;++ks){
                        nxt[2*ks]   = *(const f32x4*)(bn + ks*32);
                        nxt[2*ks+1] = *(const f32x4*)(bn + ks*32 + 4);
                    }
                }
                f32x4 acc = {0.f,0.f,0.f,0.f};
                #pragma unroll
                for (int ks=0;ks<4;++ks)
                    acc = MFMA16(cvt2(cur[2*ks], cur[2*ks+1]), w1f[ks], acc);
                #pragma unroll
                for (int m=0;m<4;++m)
                    *(__bf16*)(stg1 + swzoff(16*t + 4*q + m, colb2)) =
                        (__bf16)fmaxf(acc[m]+b1c, 0.f);
                if (t < 3){
                    #pragma unroll
                    for (int i=0;i<8;++i) cur[i] = nxt[i];
                }
            }
        }
        __syncthreads();                                    // B1: x ready
        // (b) iou = x @ Wiou^T (Wiou from LDS); apply_node(c_in=0)
        float c0c[4][4];
        #pragma unroll
        for (int t=0;t<4;++t){
            f32x4 ai={0.f,0.f,0.f,0.f}, ao=ai, au=ai;
            #pragma unroll
            for (int ks=0;ks<4;++ks){
                bf16x8 a = lds_frag(stg1, 16*t, lane, ks);
                ai = MFMA16(a, lds_frag(wiouL,       16*wave, lane, ks), ai);
                ao = MFMA16(a, lds_frag(wiouL, 128 + 16*wave, lane, ks), ao);
                au = MFMA16(a, lds_frag(wiouL, 256 + 16*wave, lane, ks), au);
            }
            #pragma unroll
            for (int m=0;m<4;++m){
                float cv = fast_sigmoid(ai[m]+W.bi)*fast_tanh(au[m]+W.bu);
                float hv = fast_sigmoid(ao[m]+W.bo)*fast_tanh(cv);
                c0c[t][m] = cv;
                *(__bf16*)(stg2 + swzoff(16*t + 4*q + m, colb2)) = (__bf16)hv;
            }
        }
        __syncthreads();                                    // B2: leaf h ready
        // (c) leaf F-gates + pair-reduce + fold -> c8loc (32 level-8 nodes)
        float red[4][2];
        #pragma unroll
        for (int t=0;t<4;++t){
            f32x4 acc = {0.f,0.f,0.f,0.f};
            #pragma unroll
            for (int ks=0;ks<4;++ks)
                acc = MFMA16(lds_frag(stg2, 16*t, lane, ks), W.uf[ks], acc);
            red[t][0] = fast_sigmoid(acc[0]+W.bfc)*c0c[t][0] + fast_sigmoid(acc[1]+W.bfc)*c0c[t][1];
            red[t][1] = fast_sigmoid(acc[2]+W.bfc)*c0c[t][2] + fast_sigmoid(acc[3]+W.bfc)*c0c[t][3];
        }
        float c8loc[2][4];
        #pragma unroll
        for (int tau=0;tau<2;++tau){
            #pragma unroll
            for (int mp=0;mp<4;++mp){
                int s   = 4*q + mp;
                int src = ((s>>1)&3)*16 + r;
                float va = __shfl(red[2*tau  ][mp&1], src, 64);
                float vb = __shfl(red[2*tau+1][mp&1], src, 64);
                c8loc[tau][mp] = (q >= 2) ? vb : va;
            }
        }
        // (d) level-8 IOU: h8 (32 rows) -> stg1 (x consumed after B2)
        #pragma unroll
        for (int tau=0;tau<2;++tau){
            f32x4 ai={0.f,0.f,0.f,0.f}, ao=ai, au=ai;
            #pragma unroll
            for (int ks=0;ks<4;++ks){
                bf16x8 a = lds_pair_frag(stg2, 32*tau + 2*r, q, ks);
                ai = MFMA16(a, W.ui[ks], ai);
                ao = MFMA16(a, W.uo[ks], ao);
                au = MFMA16(a, W.uu[ks], au);
            }
            #pragma unroll
            for (int m=0;m<4;++m){
                float cv = fast_sigmoid(ai[m]+W.bi)*fast_tanh(au[m]+W.bu) + c8loc[tau][m];
                float hv = fast_sigmoid(ao[m]+W.bo)*fast_tanh(cv);
                c8loc[tau][m] = cv;
                *(__bf16*)(stg1 + swzoff(16*tau + 4*q + m, colb2)) = (__bf16)hv;
            }
        }
        __syncthreads();                                    // B3: h8 ready
        // (e) level-7 F-gates on h8 + fold -> c7loc (16 level-7 nodes)
        float red7[2][2];
        #pragma unroll
        for (int t=0;t<2;++t){
            f32x4 acc = {0.f,0.f,0.f,0.f};
            #pragma unroll
            for (int ks=0;ks<4;++ks)
                acc = MFMA16(lds_frag(stg1, 16*t, lane, ks), W.uf[ks], acc);
            red7[t][0] = fast_sigmoid(acc[0]+W.bfc)*c8loc[t][0] + fast_sigmoid(acc[1]+W.bfc)*c8loc[t][1];
            red7[t][1] = fast_sigmoid(acc[2]+W.bfc)*c8loc[t][2] + fast_sigmoid(acc[3]+W.bfc)*c8loc[t][3];
        }
        float c7loc[4];
        #pragma unroll
        for (int mp=0;mp<4;++mp){
            int s   = 4*q + mp;
            int src = ((s>>1)&3)*16 + r;
            float va = __shfl(red7[0][mp&1], src, 64);
            float vb = __shfl(red7[1][mp&1], src, 64);
            c7loc[mp] = (q >= 2) ? vb : va;
        }
        // (f) level-7 IOU: h7 (16 rows) -> arena rows 16ci..; c7 -> c[ci]
        {
            f32x4 ai={0.f,0.f,0.f,0.f}, ao=ai, au=ai;
            #pragma unroll
            for (int ks=0;ks<4;++ks){
                bf16x8 a = lds_pair_frag(stg1, 2*r, q, ks);
                ai = MFMA16(a, W.ui[ks], ai);
                ao = MFMA16(a, W.uo[ks], ao);
                au = MFMA16(a, W.uu[ks], au);
            }
            #pragma unroll
            for (int m=0;m<4;++m){
                float cv = fast_sigmoid(ai[m]+W.bi)*fast_tanh(au[m]+W.bu) + c7loc[m];
                float hv = fast_sigmoid(ao[m]+W.bo)*fast_tanh(cv);
                c[ci][m] = cv;
                *(__bf16*)(arena + swzoff(16*ci + 4*q + m, colb2)) = (__bf16)hv;
            }
        }
        __syncthreads();                                    // B4: chunk done
    }

    // ---- levels 6..0: h ping-pongs arena <-> bufA (old Wiou slab) ----
    char* bufA = wiouL;
    level_step<64>(c, arena, bufA,  W, lane, colb2);
    level_step<32>(c, bufA,  arena, W, lane, colb2);
    level_step<16>(c, arena, bufA,  W, lane, colb2);
    level_step< 8>(c, bufA,  arena, W, lane, colb2);
    level_step< 4>(c, arena, bufA,  W, lane, colb2);
    level_step< 2>(c, bufA,  arena, W, lane, colb2);
    level_step< 1>(c, arena, bufA,  W, lane, colb2);

    // ---- out = c_root @ Wout^T + bout ----
    float* cbuf = (float*)stg2;
    if (q == 0) cbuf[colw] = c[0][0];          // root: node 0 lives in q==0,m==0
    __syncthreads();
    if (tid < 32){
        float acc = bout[tid];
        const float* wr = Wout + tid*128;
        #pragma unroll
        for (int k=0;k<128;k+=4){
            f32x4 wv = *(const f32x4*)(wr + k);
            acc += wv[0]*cbuf[k] + wv[1]*cbuf[k+1] + wv[2]*cbuf[k+2] + wv[3]*cbuf[k+3];
        }
        out[tree*32 + tid] = acc;
    }
}

extern "C" void kernel_launch(void* const* d_in, const int* in_sizes, int n_in,
                              void* d_out, int out_size, void* d_ws, size_t ws_size,
                              hipStream_t stream)
{
    (void)in_sizes; (void)n_in; (void)out_size; (void)d_ws; (void)ws_size;
    const float* feats = (const float*)d_in[0];
    const float* W1    = (const float*)d_in[2];
    const float* b1    = (const float*)d_in[3];
    const float* Wiou  = (const float*)d_in[4];
    const float* Uiou  = (const float*)d_in[5];
    const float* biou  = (const float*)d_in[6];
    const float* Uf    = (const float*)d_in[7];
    const float* bf    = (const float*)d_in[8];
    const float* Wout  = (const float*)d_in[9];
    const float* bout  = (const float*)d_in[10];
    float* out = (float*)d_out;

    const int lds = 163840;
    hipFuncSetAttribute((const void*)&treelstm_fused,
                        hipFuncAttributeMaxDynamicSharedMemorySize, lds);
    treelstm_fused<<<dim3(256), dim3(512), lds, stream>>>(
        feats, W1, b1, Wiou, Uiou, biou, Uf, bf, Wout, bout, out);
}